// Round 2
// baseline (926.946 us; speedup 1.0000x reference)
//
#include <hip/hip_runtime.h>
#include <math.h>

#define B_   8
#define CIN  256
#define COUT 256
#define H_   64
#define W_   64
#define HO   62
#define WO   62
#define SDIM 512
#define CI_T 8

// ws layout (floats):
// s:       [0, 2048)
// dm:      [2048, 4096)
// wsq:     [4096, 69632)
// wtrans:  [69632, 659456)          (256ci * 9k * 256co)
// convout: [659456, 8531968)        (8*256*62*62)

__global__ void mod_kernel(const float* __restrict__ style, const float* __restrict__ mod_w,
                           const float* __restrict__ mod_b, float* __restrict__ s_out) {
    int wid = blockIdx.x * 4 + (threadIdx.x >> 6);
    int lane = threadIdx.x & 63;
    int b = wid >> 8, ci = wid & 255;
    float acc = 0.f;
    const float* st = style + b * SDIM;
    const float* mw = mod_w + ci * SDIM;
    for (int i = 0; i < SDIM; i += 64) acc += st[i + lane] * mw[i + lane];
    for (int m = 32; m >= 1; m >>= 1) acc += __shfl_xor(acc, m, 64);
    if (lane == 0) s_out[wid] = acc * 0.04419417382415922f + mod_b[ci]; // 1/sqrt(512)
}

__global__ void wsq_kernel(const float* __restrict__ cw, float* __restrict__ wsq,
                           float* __restrict__ wtrans) {
    int idx = blockIdx.x * blockDim.x + threadIdx.x; // 65536 = co*256+ci
    int co = idx >> 8, ci = idx & 255;
    const float* p = cw + (size_t)idx * 9;
    float ss = 0.f;
#pragma unroll
    for (int k = 0; k < 9; ++k) {
        float v = p[k];
        ss += v * v;
        wtrans[(ci * 9 + k) * COUT + co] = v;
    }
    wsq[idx] = ss;
}

__global__ void demod_kernel(const float* __restrict__ s_in, const float* __restrict__ wsq,
                             float* __restrict__ dm) {
    int wid = blockIdx.x * 4 + (threadIdx.x >> 6);
    int lane = threadIdx.x & 63;
    int b = wid >> 8, co = wid & 255;
    float acc = 0.f;
    for (int i = 0; i < CIN; i += 64) {
        float sv = s_in[b * CIN + i + lane];
        acc += sv * sv * wsq[co * CIN + i + lane];
    }
    for (int m = 32; m >= 1; m >>= 1) acc += __shfl_xor(acc, m, 64);
    if (lane == 0) {
        const float scale = 0.020833333333333332f; // 1/48 = 1/sqrt(2304)
        float demod = rsqrtf(scale * scale * acc + 1e-8f);
        dm[wid] = demod * scale / (1.f + 1e-8f);
    }
}

__global__ __launch_bounds__(256) void conv_kernel(
        const float* __restrict__ x, const float* __restrict__ wtrans,
        const float* __restrict__ s_in, const float* __restrict__ dm,
        const float* __restrict__ bias, float* __restrict__ convout) {
    __shared__ float in_t[CI_T][18][19];
    __shared__ __align__(16) float w_t[CI_T][9][64];
    int tid = threadIdx.x;
    int b = blockIdx.z;
    int co0 = blockIdx.y * 64;
    int ty = blockIdx.x >> 2, tx = blockIdx.x & 3;
    int y0 = ty * 16, x0 = tx * 16;
    int cog = tid & 7;          // 8 co-groups of 8
    int spg = tid >> 3;         // 32 spatial groups of 8
    int row = spg >> 1, ch = spg & 1;

    float acc[8][8];
#pragma unroll
    for (int c = 0; c < 8; ++c)
#pragma unroll
        for (int j = 0; j < 8; ++j) acc[c][j] = 0.f;

    for (int ci0 = 0; ci0 < CIN; ci0 += CI_T) {
        for (int idx = tid; idx < CI_T * 18 * 18; idx += 256) {
            int ci = idx / 324;
            int rem = idx - ci * 324;
            int r = rem / 18, cc = rem - r * 18;
            int gy = y0 + r, gx = x0 + cc;
            float v = 0.f;
            if (gy < H_ && gx < W_)
                v = x[(((size_t)(b * CIN) + ci0 + ci) * H_ + gy) * W_ + gx] *
                    s_in[b * CIN + ci0 + ci];
            in_t[ci][r][cc] = v;
        }
        for (int idx = tid; idx < CI_T * 9 * 64; idx += 256) {
            int ci = idx / 576;
            int rem = idx - ci * 576;
            int k = rem >> 6, co = rem & 63;
            w_t[ci][k][co] = wtrans[((ci0 + ci) * 9 + k) * COUT + co0 + co];
        }
        __syncthreads();
#pragma unroll
        for (int cc = 0; cc < CI_T; ++cc) {
            float xr[3][10];
#pragma unroll
            for (int ky = 0; ky < 3; ++ky)
#pragma unroll
                for (int t = 0; t < 10; ++t)
                    xr[ky][t] = in_t[cc][row + ky][ch * 8 + t];
#pragma unroll
            for (int ky = 0; ky < 3; ++ky)
#pragma unroll
                for (int kx = 0; kx < 3; ++kx) {
                    const float4* wp = (const float4*)&w_t[cc][ky * 3 + kx][cog * 8];
                    float4 w0 = wp[0], w1 = wp[1];
                    float wv[8] = {w0.x, w0.y, w0.z, w0.w, w1.x, w1.y, w1.z, w1.w};
#pragma unroll
                    for (int c = 0; c < 8; ++c)
#pragma unroll
                        for (int j = 0; j < 8; ++j)
                            acc[c][j] += wv[c] * xr[ky][j + kx];
                }
        }
        __syncthreads();
    }
    int y = y0 + row;
#pragma unroll
    for (int c = 0; c < 8; ++c) {
        int co = co0 + cog * 8 + c;
        float dmv = dm[b * COUT + co];
        float bv = bias[co];
        if (y < HO) {
#pragma unroll
            for (int j = 0; j < 8; ++j) {
                int xx = x0 + ch * 8 + j;
                if (xx < WO)
                    convout[(((size_t)(b * COUT) + co) * HO + y) * WO + xx] =
                        acc[c][j] * dmv + bv;
            }
        }
    }
}

// Fused upfirdn(up2,x) -> upfirdn(up2,y) -> leaky*sqrt2 -> down2(x) -> down2(y)
// per (b,c) plane. 62x62 in -> 64x64 out.
__global__ __launch_bounds__(256) void filter_kernel(
        const float* __restrict__ convout, const float* __restrict__ upf,
        const float* __restrict__ dnf, float* __restrict__ out) {
    // lds0: cin (62 rows, stride 65, floats [0,4030)) then bufA (62 rows, stride 132,
    // floats [4030,12214)). bufB (128 rows, stride 65, floats [0,8320)) aliases cin+
    // early bufA rows; phase-locked barriers guarantee bufB row writes (<=520*(it+1))
    // never reach bufA rows still needed (>= 3502+528*it). cin dead before bufB starts.
    __shared__ float lds0[12214];
    __shared__ __align__(16) float trow2[4][2][144];
    __shared__ float uf[12], df[12];
    float* cin  = lds0;
    float* bufA = lds0 + 4030;
    float* bufB = lds0;
    int tid = threadIdx.x;
    int p = blockIdx.x;
    const float* src = convout + (size_t)p * (HO * WO);
    float* dst = out + (size_t)p * (64 * 64);
    if (tid < 12) { uf[tid] = upf[tid] * 2.f; df[tid] = dnf[tid]; }
    for (int idx = tid; idx < HO * WO; idx += 256) {
        int y = idx / 62, xx = idx - y * 62;
        cin[y * 65 + xx] = src[idx];
    }
    __syncthreads();
    // up-x: out[2m]=sum_v uf[2v+1]*x[m+1-v]; out[2m+1]=sum_v uf[2v]*x[m+2-v]
    for (int task = tid; task < 62 * 16; task += 256) {
        int y = task >> 4, g = task & 15;
        int base = 4 * g - 4;
        float xv[10];
#pragma unroll
        for (int t = 0; t < 10; ++t) {
            int i = base + t;
            xv[t] = (i >= 0 && i < 62) ? cin[y * 65 + i] : 0.f;
        }
#pragma unroll
        for (int dd = 0; dd < 4; ++dd) {
            float oe = 0.f, oo = 0.f;
#pragma unroll
            for (int v = 0; v < 6; ++v) {
                oe += uf[2 * v + 1] * xv[dd + 5 - v];
                oo += uf[2 * v] * xv[dd + 6 - v];
            }
            int j = 8 * g + 2 * dd;
            bufA[y * 132 + j] = oe;
            bufA[y * 132 + j + 1] = oo;
        }
    }
    __syncthreads();
    // up-y + leaky + down-x, row-pair (2n, 2n+1) per wave per iteration
    int wid = tid >> 6, lane = tid & 63;
    float* tr0 = &trow2[wid][0][0];
    float* tr1 = &trow2[wid][1][0];
    if (lane < 5) { tr0[lane] = 0.f; tr1[lane] = 0.f; }
    if (lane < 7) { tr0[133 + lane] = 0.f; tr1[133 + lane] = 0.f; }
    const float SQ2 = 1.4142135623730951f;
    for (int it = 0; it < 16; ++it) {
        int n = 4 * it + wid;
#pragma unroll
        for (int half = 0; half < 2; ++half) {
            int j = lane + 64 * half;
            float xv[7];
#pragma unroll
            for (int d = 0; d < 7; ++d) {
                int i = n - 4 + d;
                xv[d] = (i >= 0 && i < 62) ? bufA[i * 132 + j] : 0.f;
            }
            float te = 0.f, to = 0.f;
#pragma unroll
            for (int d = 0; d < 6; ++d) te += uf[11 - 2 * d] * xv[d];
#pragma unroll
            for (int d = 1; d < 7; ++d) to += uf[12 - 2 * d] * xv[d];
            te = (te >= 0.f ? te : 0.2f * te) * SQ2;
            to = (to >= 0.f ? to : 0.2f * to) * SQ2;
            tr0[5 + j] = te;
            tr1[5 + j] = to;
        }
        __syncthreads();
        {
            int xo = lane;
            const float2* a0 = (const float2*)&tr0[2 * xo];
            const float2* a1 = (const float2*)&tr1[2 * xo];
            float v0[12], v1[12];
#pragma unroll
            for (int q = 0; q < 6; ++q) {
                float2 u0 = a0[q], u1 = a1[q];
                v0[2 * q] = u0.x; v0[2 * q + 1] = u0.y;
                v1[2 * q] = u1.x; v1[2 * q + 1] = u1.y;
            }
            float s0 = 0.f, s1 = 0.f;
#pragma unroll
            for (int u = 0; u < 12; ++u) {
                s0 += df[u] * v0[11 - u];
                s1 += df[u] * v1[11 - u];
            }
            bufB[(2 * n) * 65 + xo] = s0;
            bufB[(2 * n + 1) * 65 + xo] = s1;
        }
        __syncthreads();
    }
    // down-y + store: out[yo] = sum_u df[u]*rows[2yo+6-u]
    for (int idx = tid; idx < 64 * 64; idx += 256) {
        int yo = idx >> 6, xx = idx & 63;
        float acc2 = 0.f;
#pragma unroll
        for (int u = 0; u < 12; ++u) {
            int rr = 2 * yo + 6 - u;
            if (rr >= 0 && rr < 128) acc2 += df[u] * bufB[rr * 65 + xx];
        }
        dst[idx] = acc2;
    }
}

extern "C" void kernel_launch(void* const* d_in, const int* in_sizes, int n_in,
                              void* d_out, int out_size, void* d_ws, size_t ws_size,
                              hipStream_t stream) {
    const float* input       = (const float*)d_in[0];
    const float* style       = (const float*)d_in[1];
    const float* conv_weight = (const float*)d_in[2];
    const float* mod_w       = (const float*)d_in[3];
    const float* mod_b       = (const float*)d_in[4];
    const float* bias        = (const float*)d_in[5];
    const float* up_filter   = (const float*)d_in[6];
    const float* down_filter = (const float*)d_in[7];
    float* ws = (float*)d_ws;
    float* out = (float*)d_out;
    float* s_buf   = ws;
    float* dm      = ws + 2048;
    float* wsq     = ws + 4096;
    float* wtrans  = ws + 69632;
    float* convout = ws + 659456;

    hipLaunchKernelGGL(mod_kernel, dim3(512), dim3(256), 0, stream, style, mod_w, mod_b, s_buf);
    hipLaunchKernelGGL(wsq_kernel, dim3(256), dim3(256), 0, stream, conv_weight, wsq, wtrans);
    hipLaunchKernelGGL(demod_kernel, dim3(512), dim3(256), 0, stream, s_buf, wsq, dm);
    hipLaunchKernelGGL(conv_kernel, dim3(16, 4, 8), dim3(256), 0, stream,
                       input, wtrans, s_buf, dm, bias, convout);
    hipLaunchKernelGGL(filter_kernel, dim3(2048), dim3(256), 0, stream,
                       convout, up_filter, down_filter, out);
}

// Round 3
// 283.899 us; speedup vs baseline: 3.2651x; 3.2651x over previous
//
#include <hip/hip_runtime.h>
#include <math.h>

#define B_   8
#define CIN  256
#define COUT 256
#define H_   64
#define W_   64
#define HO   62
#define WO   62
#define SDIM 512

// convout padded: [b][co][62][64]
#define CSTRIDE 64

typedef __attribute__((ext_vector_type(8))) short bf16x8;
typedef __attribute__((ext_vector_type(4))) float f32x4;

__device__ __forceinline__ unsigned short f2bf(float f) {
    unsigned int u = __float_as_uint(f);
    u += 0x7fffu + ((u >> 16) & 1u);
    return (unsigned short)(u >> 16);
}
__device__ __forceinline__ float bf2f(unsigned short h) {
    return __uint_as_float(((unsigned int)h) << 16);
}

// ws layout (floats):
// s:       [0, 2048)
// dm:      [2048, 4096)
// wsq:     [4096, 69632)
// wh:      [69632, 364544)    (9*256*256 ushort)
// wl:      [364544, 659456)
// convout: [659456, 8785920)  (8*256*62*64)

__global__ void mod_kernel(const float* __restrict__ style, const float* __restrict__ mod_w,
                           const float* __restrict__ mod_b, float* __restrict__ s_out) {
    int wid = blockIdx.x * 4 + (threadIdx.x >> 6);
    int lane = threadIdx.x & 63;
    int b = wid >> 8, ci = wid & 255;
    float acc = 0.f;
    const float* st = style + b * SDIM;
    const float* mw = mod_w + ci * SDIM;
    for (int i = 0; i < SDIM; i += 64) acc += st[i + lane] * mw[i + lane];
    for (int m = 32; m >= 1; m >>= 1) acc += __shfl_xor(acc, m, 64);
    if (lane == 0) s_out[wid] = acc * 0.04419417382415922f + mod_b[ci]; // 1/sqrt(512)
}

__global__ void wsplit_kernel(const float* __restrict__ cw, float* __restrict__ wsq,
                              unsigned short* __restrict__ wh, unsigned short* __restrict__ wl) {
    int idx = blockIdx.x * blockDim.x + threadIdx.x; // co*256+ci
    int co = idx >> 8, ci = idx & 255;
    const float* p = cw + (size_t)idx * 9;
    float ss = 0.f;
#pragma unroll
    for (int k = 0; k < 9; ++k) {
        float v = p[k];
        ss += v * v;
        unsigned short h = f2bf(v);
        unsigned short l = f2bf(v - bf2f(h));
        wh[(k * COUT + co) * CIN + ci] = h;
        wl[(k * COUT + co) * CIN + ci] = l;
    }
    wsq[idx] = ss;
}

__global__ void demod_kernel(const float* __restrict__ s_in, const float* __restrict__ wsq,
                             float* __restrict__ dm) {
    int wid = blockIdx.x * 4 + (threadIdx.x >> 6);
    int lane = threadIdx.x & 63;
    int b = wid >> 8, co = wid & 255;
    float acc = 0.f;
    for (int i = 0; i < CIN; i += 64) {
        float sv = s_in[b * CIN + i + lane];
        acc += sv * sv * wsq[co * CIN + i + lane];
    }
    for (int m = 32; m >= 1; m >>= 1) acc += __shfl_xor(acc, m, 64);
    if (lane == 0) {
        const float scale = 0.020833333333333332f; // 1/48 = 1/sqrt(2304)
        float demod = rsqrtf(scale * scale * acc + 1e-8f);
        dm[wid] = demod * scale / (1.f + 1e-8f);
    }
}

// Implicit-GEMM modulated conv via 9-shift decomposition, bf16 hi/lo split MFMA.
// Block: 4 waves (2 wy x 2 wc); tile: 8 y-rows x 16 x x 128 co.
// Wave: 4 y-row M-tiles x 4 co N-tiles of mfma_f32_16x16x32_bf16.
__global__ __launch_bounds__(256) void conv_mfma(
        const float* __restrict__ x, const unsigned short* __restrict__ wh,
        const unsigned short* __restrict__ wl, const float* __restrict__ s_in,
        const float* __restrict__ dm, const float* __restrict__ bias,
        float* __restrict__ convout) {
    extern __shared__ short lds[];
    short* Ah = lds;                  // [10][18][32] (chunk-swizzled)
    short* Al = lds + 5760;
    short* Bh = lds + 11520;          // [3][128][32] (chunk-swizzled)
    short* Bl = lds + 23808;
    __shared__ float s_loc[CIN];

    int tid = threadIdx.x;
    int b = blockIdx.z;
    int co0 = blockIdx.y * 128;
    int sx = blockIdx.x & 3, sy = blockIdx.x >> 2;
    int x0 = sx * 16, y0 = sy * 8;
    int wid = tid >> 6, lane = tid & 63;
    int wy = wid >> 1, wc = wid & 1;
    int lrow = lane & 15, lch = lane >> 4;

    for (int i = tid; i < CIN; i += 256) s_loc[i] = s_in[b * CIN + i];
    __syncthreads();

    f32x4 acc[4][4];
#pragma unroll
    for (int i = 0; i < 4; ++i)
#pragma unroll
        for (int j = 0; j < 4; ++j) acc[i][j] = (f32x4){0.f, 0.f, 0.f, 0.f};

    for (int ks = 0; ks < 8; ++ks) {
        int ci0 = ks * 32;
#pragma unroll 1
        for (int ky = 0; ky < 3; ++ky) {
            if (ky == 0) {
                // stage A: 32ci x 10row x 18col, scale by s, split hi/lo
                for (int e = tid; e < 5760; e += 256) {
                    int ci = e / 180;
                    int rem = e - ci * 180;
                    int row = rem / 18, col = rem - row * 18;
                    int yy = y0 + row, xx = x0 + col;
                    float v = 0.f;
                    if (yy < H_ && xx < W_)
                        v = x[(((size_t)b * CIN + ci0 + ci) * H_ + yy) * W_ + xx] *
                            s_loc[ci0 + ci];
                    unsigned short h = f2bf(v);
                    unsigned short l2 = f2bf(v - bf2f(h));
                    int off = (row * 18 + col) * 32 + (((ci >> 3) ^ (col & 3)) << 3) + (ci & 7);
                    Ah[off] = (short)h;
                    Al[off] = (short)l2;
                }
            }
            // stage B: 2 arrays * 3kx * 128co * 4 chunks of 8 bf16
            for (int u = tid; u < 3072; u += 256) {
                int a = (u >= 1536);
                int r = u - a * 1536;
                int kx = r >> 9;
                int r2 = r & 511;
                int co = r2 >> 2, ch = r2 & 3;
                const unsigned short* src = a ? wl : wh;
                const uint4 val = *(const uint4*)(src +
                    ((size_t)((ky * 3 + kx) * COUT + co0 + co)) * CIN + ci0 + ch * 8);
                short* dstb = a ? Bl : Bh;
                int boff = ((kx << 7) + co) * 32 + ((ch ^ (co & 3)) << 3);
                *(uint4*)(dstb + boff) = val;
            }
            __syncthreads();
#pragma unroll
            for (int kx = 0; kx < 3; ++kx) {
                int colL = lrow + kx;
                int asw = (lch ^ (colL & 3)) << 3;
                bf16x8 ahf[4], alf[4];
#pragma unroll
                for (int yr = 0; yr < 4; ++yr) {
                    int rr = wy * 4 + yr + ky;
                    int off = (rr * 18 + colL) * 32 + asw;
                    ahf[yr] = *(const bf16x8*)(Ah + off);
                    alf[yr] = *(const bf16x8*)(Al + off);
                }
#pragma unroll
                for (int nt = 0; nt < 4; ++nt) {
                    int col = wc * 64 + nt * 16 + lrow;
                    int boff = ((kx << 7) + col) * 32 + ((lch ^ (col & 3)) << 3);
                    bf16x8 bhf = *(const bf16x8*)(Bh + boff);
                    bf16x8 blf = *(const bf16x8*)(Bl + boff);
#pragma unroll
                    for (int yr = 0; yr < 4; ++yr) {
                        acc[yr][nt] = __builtin_amdgcn_mfma_f32_16x16x32_bf16(ahf[yr], bhf, acc[yr][nt], 0, 0, 0);
                        acc[yr][nt] = __builtin_amdgcn_mfma_f32_16x16x32_bf16(ahf[yr], blf, acc[yr][nt], 0, 0, 0);
                        acc[yr][nt] = __builtin_amdgcn_mfma_f32_16x16x32_bf16(alf[yr], bhf, acc[yr][nt], 0, 0, 0);
                    }
                }
            }
            __syncthreads();
        }
    }

    // epilogue: D row = x-pos = 4*lch + j, D col = co = 16*nt + lrow
    int xs4 = x0 + (lch << 2);
#pragma unroll
    for (int nt = 0; nt < 4; ++nt) {
        int co = co0 + wc * 64 + nt * 16 + lrow;
        float dmv = dm[b * COUT + co];
        float bv = bias[co];
#pragma unroll
        for (int yr = 0; yr < 4; ++yr) {
            int y = y0 + wy * 4 + yr;
            if (y < HO) {
                f32x4 o;
#pragma unroll
                for (int j = 0; j < 4; ++j) o[j] = acc[yr][nt][j] * dmv + bv;
                *(f32x4*)(convout + ((size_t)(b * COUT + co) * HO + y) * CSTRIDE + xs4) = o;
            }
        }
    }
}

// Fused upfirdn(up2,x) -> upfirdn(up2,y) -> leaky*sqrt2 -> down2(x) -> down2(y)
// per (b,c) plane. 62x62 in (stride-64 rows) -> 64x64 out.
__global__ __launch_bounds__(256) void filter_kernel(
        const float* __restrict__ convout, const float* __restrict__ upf,
        const float* __restrict__ dnf, float* __restrict__ out) {
    __shared__ float lds0[12214];
    __shared__ __align__(16) float trow2[4][2][144];
    __shared__ float uf[12], df[12];
    float* cin  = lds0;
    float* bufA = lds0 + 4030;
    float* bufB = lds0;
    int tid = threadIdx.x;
    int p = blockIdx.x;
    const float* src = convout + (size_t)p * (HO * CSTRIDE);
    float* dst = out + (size_t)p * (64 * 64);
    if (tid < 12) { uf[tid] = upf[tid] * 2.f; df[tid] = dnf[tid]; }
    for (int idx = tid; idx < HO * WO; idx += 256) {
        int y = idx / 62, xx = idx - y * 62;
        cin[y * 65 + xx] = src[y * CSTRIDE + xx];
    }
    __syncthreads();
    for (int task = tid; task < 62 * 16; task += 256) {
        int y = task >> 4, g = task & 15;
        int base = 4 * g - 4;
        float xv[10];
#pragma unroll
        for (int t = 0; t < 10; ++t) {
            int i = base + t;
            xv[t] = (i >= 0 && i < 62) ? cin[y * 65 + i] : 0.f;
        }
#pragma unroll
        for (int dd = 0; dd < 4; ++dd) {
            float oe = 0.f, oo = 0.f;
#pragma unroll
            for (int v = 0; v < 6; ++v) {
                oe += uf[2 * v + 1] * xv[dd + 5 - v];
                oo += uf[2 * v] * xv[dd + 6 - v];
            }
            int j = 8 * g + 2 * dd;
            bufA[y * 132 + j] = oe;
            bufA[y * 132 + j + 1] = oo;
        }
    }
    __syncthreads();
    int wid = tid >> 6, lane = tid & 63;
    float* tr0 = &trow2[wid][0][0];
    float* tr1 = &trow2[wid][1][0];
    if (lane < 5) { tr0[lane] = 0.f; tr1[lane] = 0.f; }
    if (lane < 7) { tr0[133 + lane] = 0.f; tr1[133 + lane] = 0.f; }
    const float SQ2 = 1.4142135623730951f;
    for (int it = 0; it < 16; ++it) {
        int n = 4 * it + wid;
#pragma unroll
        for (int half = 0; half < 2; ++half) {
            int j = lane + 64 * half;
            float xv[7];
#pragma unroll
            for (int d = 0; d < 7; ++d) {
                int i = n - 4 + d;
                xv[d] = (i >= 0 && i < 62) ? bufA[i * 132 + j] : 0.f;
            }
            float te = 0.f, to = 0.f;
#pragma unroll
            for (int d = 0; d < 6; ++d) te += uf[11 - 2 * d] * xv[d];
#pragma unroll
            for (int d = 1; d < 7; ++d) to += uf[12 - 2 * d] * xv[d];
            te = (te >= 0.f ? te : 0.2f * te) * SQ2;
            to = (to >= 0.f ? to : 0.2f * to) * SQ2;
            tr0[5 + j] = te;
            tr1[5 + j] = to;
        }
        __syncthreads();
        {
            int xo = lane;
            const float2* a0 = (const float2*)&tr0[2 * xo];
            const float2* a1 = (const float2*)&tr1[2 * xo];
            float v0[12], v1[12];
#pragma unroll
            for (int q = 0; q < 6; ++q) {
                float2 u0 = a0[q], u1 = a1[q];
                v0[2 * q] = u0.x; v0[2 * q + 1] = u0.y;
                v1[2 * q] = u1.x; v1[2 * q + 1] = u1.y;
            }
            float s0 = 0.f, s1 = 0.f;
#pragma unroll
            for (int u = 0; u < 12; ++u) {
                s0 += df[u] * v0[11 - u];
                s1 += df[u] * v1[11 - u];
            }
            bufB[(2 * n) * 65 + xo] = s0;
            bufB[(2 * n + 1) * 65 + xo] = s1;
        }
        __syncthreads();
    }
    for (int idx = tid; idx < 64 * 64; idx += 256) {
        int yo = idx >> 6, xx = idx & 63;
        float acc2 = 0.f;
#pragma unroll
        for (int u = 0; u < 12; ++u) {
            int rr = 2 * yo + 6 - u;
            if (rr >= 0 && rr < 128) acc2 += df[u] * bufB[rr * 65 + xx];
        }
        dst[idx] = acc2;
    }
}

extern "C" void kernel_launch(void* const* d_in, const int* in_sizes, int n_in,
                              void* d_out, int out_size, void* d_ws, size_t ws_size,
                              hipStream_t stream) {
    const float* input       = (const float*)d_in[0];
    const float* style       = (const float*)d_in[1];
    const float* conv_weight = (const float*)d_in[2];
    const float* mod_w       = (const float*)d_in[3];
    const float* mod_b       = (const float*)d_in[4];
    const float* bias        = (const float*)d_in[5];
    const float* up_filter   = (const float*)d_in[6];
    const float* down_filter = (const float*)d_in[7];
    float* ws  = (float*)d_ws;
    float* out = (float*)d_out;
    float* s_buf   = ws;
    float* dm      = ws + 2048;
    float* wsq     = ws + 4096;
    unsigned short* wh = (unsigned short*)(ws + 69632);
    unsigned short* wl = (unsigned short*)(ws + 364544);
    float* convout = ws + 659456;

    hipLaunchKernelGGL(mod_kernel, dim3(512), dim3(256), 0, stream, style, mod_w, mod_b, s_buf);
    hipLaunchKernelGGL(wsplit_kernel, dim3(256), dim3(256), 0, stream, conv_weight, wsq, wh, wl);
    hipLaunchKernelGGL(demod_kernel, dim3(512), dim3(256), 0, stream, s_buf, wsq, dm);
    hipLaunchKernelGGL(conv_mfma, dim3(32, 2, 8), dim3(256), 72192, stream,
                       input, wh, wl, s_buf, dm, bias, convout);
    hipLaunchKernelGGL(filter_kernel, dim3(2048), dim3(256), 0, stream,
                       convout, up_filter, down_filter, out);
}

// Round 4
// 239.634 us; speedup vs baseline: 3.8682x; 1.1847x over previous
//
#include <hip/hip_runtime.h>
#include <math.h>

#define B_   8
#define CIN  256
#define COUT 256
#define H_   64
#define W_   64
#define HO   62
#define WO   62
#define SDIM 512

// convout padded: [b][co][62][64] bf16
#define CSTRIDE 64
#define WHL_OFF 589824   // ushorts between wh and wl

typedef __attribute__((ext_vector_type(8))) short bf16x8;
typedef __attribute__((ext_vector_type(4))) float f32x4;

__device__ __forceinline__ unsigned short f2bf(float f) {
    unsigned int u = __float_as_uint(f);
    u += 0x7fffu + ((u >> 16) & 1u);
    return (unsigned short)(u >> 16);
}
__device__ __forceinline__ float bf2f(unsigned short h) {
    return __uint_as_float(((unsigned int)h) << 16);
}

// ws layout (floats):
// s:       [0, 2048)
// dm:      [2048, 4096)
// wsq:     [4096, 69632)
// whl:     [69632, 659456)     (2 * 9*256*256 ushort: wh then wl)
// xh:      [659456, 4853760)   (8*64*64*256 ushort)
// xl:      [4853760, 9048064)
// convout: [9048064, 13111296) (8*256*62*64 ushort)

__global__ void mod_kernel(const float* __restrict__ style, const float* __restrict__ mod_w,
                           const float* __restrict__ mod_b, float* __restrict__ s_out) {
    int wid = blockIdx.x * 4 + (threadIdx.x >> 6);
    int lane = threadIdx.x & 63;
    int b = wid >> 8, ci = wid & 255;
    float acc = 0.f;
    const float* st = style + b * SDIM;
    const float* mw = mod_w + ci * SDIM;
    for (int i = 0; i < SDIM; i += 64) acc += st[i + lane] * mw[i + lane];
    for (int m = 32; m >= 1; m >>= 1) acc += __shfl_xor(acc, m, 64);
    if (lane == 0) s_out[wid] = acc * 0.04419417382415922f + mod_b[ci]; // 1/sqrt(512)
}

__global__ void wsplit_kernel(const float* __restrict__ cw, float* __restrict__ wsq,
                              unsigned short* __restrict__ whl) {
    int idx = blockIdx.x * blockDim.x + threadIdx.x; // co*256+ci
    int co = idx >> 8, ci = idx & 255;
    const float* p = cw + (size_t)idx * 9;
    float ss = 0.f;
#pragma unroll
    for (int k = 0; k < 9; ++k) {
        float v = p[k];
        ss += v * v;
        unsigned short h = f2bf(v);
        unsigned short l = f2bf(v - bf2f(h));
        whl[(k * COUT + co) * CIN + ci] = h;
        whl[WHL_OFF + (k * COUT + co) * CIN + ci] = l;
    }
    wsq[idx] = ss;
}

__global__ void demod_kernel(const float* __restrict__ s_in, const float* __restrict__ wsq,
                             float* __restrict__ dm) {
    int wid = blockIdx.x * 4 + (threadIdx.x >> 6);
    int lane = threadIdx.x & 63;
    int b = wid >> 8, co = wid & 255;
    float acc = 0.f;
    for (int i = 0; i < CIN; i += 64) {
        float sv = s_in[b * CIN + i + lane];
        acc += sv * sv * wsq[co * CIN + i + lane];
    }
    for (int m = 32; m >= 1; m >>= 1) acc += __shfl_xor(acc, m, 64);
    if (lane == 0) {
        const float scale = 0.020833333333333332f; // 1/48 = 1/sqrt(2304)
        float demod = rsqrtf(scale * scale * acc + 1e-8f);
        dm[wid] = demod * scale / (1.f + 1e-8f);
    }
}

// Transpose+scale+split: x[b][ci][y][x] f32 -> xh/xl[b][y][x][ci] bf16.
// One block per (b,y) row; LDS tile [128ci][65] f32, two halves.
__global__ __launch_bounds__(256) void xsplit_kernel(
        const float* __restrict__ x, const float* __restrict__ s_in,
        unsigned short* __restrict__ xh, unsigned short* __restrict__ xl) {
    __shared__ float tile[128 * 65];
    __shared__ float s_loc[256];
    int b = blockIdx.x >> 6;
    int y = blockIdx.x & 63;
    int tid = threadIdx.x;
    s_loc[tid] = s_in[(b << 8) + tid];
    __syncthreads();
    for (int half = 0; half < 2; ++half) {
        int cb = half << 7;
        for (int f = tid; f < 2048; f += 256) {
            int ci = f >> 4, x4 = (f & 15) << 2;
            float4 v = *(const float4*)(x + ((((size_t)b << 8) + cb + ci) << 12) + (y << 6) + x4);
            float sv = s_loc[cb + ci];
            float* t = tile + ci * 65 + x4;
            t[0] = v.x * sv; t[1] = v.y * sv; t[2] = v.z * sv; t[3] = v.w * sv;
        }
        __syncthreads();
        for (int g = tid; g < 1024; g += 256) {
            int c = g & 15, xx = g >> 4;   // c: 8-ci chunk, xx: x position
            unsigned int hw[4], lw[4];
#pragma unroll
            for (int q = 0; q < 4; ++q) {
                float v0 = tile[(c * 8 + 2 * q) * 65 + xx];
                float v1 = tile[(c * 8 + 2 * q + 1) * 65 + xx];
                unsigned short h0 = f2bf(v0), h1 = f2bf(v1);
                unsigned short l0 = f2bf(v0 - bf2f(h0)), l1 = f2bf(v1 - bf2f(h1));
                hw[q] = (unsigned int)h0 | ((unsigned int)h1 << 16);
                lw[q] = (unsigned int)l0 | ((unsigned int)l1 << 16);
            }
            int o = ((((b << 6) + y) << 6) + xx) * 256 + cb + (c << 3);
            *(uint4*)(xh + o) = make_uint4(hw[0], hw[1], hw[2], hw[3]);
            *(uint4*)(xl + o) = make_uint4(lw[0], lw[1], lw[2], lw[3]);
        }
        __syncthreads();
    }
}

// Implicit-GEMM modulated conv, bf16 hi/lo split MFMA (hh+hl+lh).
// Block: 4 waves (2 wy x 2 wc); tile: 8 y x 16 x x 128 co.
__global__ __launch_bounds__(256) void conv_mfma(
        const unsigned short* __restrict__ xh, const unsigned short* __restrict__ xl,
        const unsigned short* __restrict__ whl, const float* __restrict__ dm,
        const float* __restrict__ bias, unsigned short* __restrict__ convout) {
    extern __shared__ short lds[];
    short* Ah = lds;            // [10][18][4 slot][8]
    short* Al = lds + 5760;
    short* Bb = lds + 11520;    // [2 a][3 kx][128 co][4 slot][8]

    int tid = threadIdx.x;
    int b = blockIdx.z;
    int co0 = blockIdx.y << 7;
    int sx = blockIdx.x & 3, sy = blockIdx.x >> 2;
    int x0 = sx << 4, y0 = sy << 3;
    int wid = tid >> 6, lane = tid & 63;
    int wy = wid >> 1, wc = wid & 1;
    int lrow = lane & 15, lch = lane >> 4;

    // precompute B-staging source offsets (ushort index into whl)
    int bsrc[12];
#pragma unroll
    for (int k = 0; k < 12; ++k) {
        int u = tid + (k << 8);
        int a = (u >= 1536);
        int r = u - a * 1536;
        int kx = r >> 9;
        int col = (r & 511) >> 2;
        int ch = r & 3;
        int cs = ch ^ (col & 3);
        bsrc[k] = a * WHL_OFF + (kx << 16) + ((co0 + col) << 8) + (cs << 3);
    }

    f32x4 acc[4][4];
#pragma unroll
    for (int i = 0; i < 4; ++i)
#pragma unroll
        for (int j = 0; j < 4; ++j) acc[i][j] = (f32x4){0.f, 0.f, 0.f, 0.f};

    for (int ks = 0; ks < 8; ++ks) {
        int ci0 = ks << 5;
#pragma unroll 1
        for (int ky = 0; ky < 3; ++ky) {
            if (ky == 0) {
                // stage A: 2 arrays * 10row * 18col * 4 chunks of 8 ci
                for (int e = tid; e < 1440; e += 256) {
                    int a = (e >= 720);
                    int r = e - a * 720;
                    int ch = r & 3;
                    int t2 = r >> 2;
                    int col = t2 % 18, row = t2 / 18;
                    int yy = y0 + row, xx = x0 + col;
                    uint4 v = make_uint4(0u, 0u, 0u, 0u);
                    if (yy < 64 && xx < 64) {
                        const unsigned short* sp = a ? xl : xh;
                        v = *(const uint4*)(sp + ((((b << 6) + yy) << 6) + xx) * 256 + ci0 + (ch << 3));
                    }
                    int off = (row * 18 + col) * 32 + ((ch ^ (col & 3)) << 3);
                    *(uint4*)((a ? Al : Ah) + off) = v;
                }
            }
            // stage B: 12 uint4 per thread, precomputed sources, linear LDS dest
            int dyn = ky * 196608 + ci0;
#pragma unroll
            for (int k = 0; k < 12; ++k) {
                uint4 v = *(const uint4*)(whl + bsrc[k] + dyn);
                *(uint4*)(Bb + ((tid + (k << 8)) << 3)) = v;
            }
            __syncthreads();
#pragma unroll
            for (int kx = 0; kx < 3; ++kx) {
                int colL = lrow + kx;
                int asw = (lch ^ (colL & 3)) << 3;
                bf16x8 ahf[4], alf[4];
#pragma unroll
                for (int yr = 0; yr < 4; ++yr) {
                    int rr = wy * 4 + yr + ky;
                    int off = (rr * 18 + colL) * 32 + asw;
                    ahf[yr] = *(const bf16x8*)(Ah + off);
                    alf[yr] = *(const bf16x8*)(Al + off);
                }
#pragma unroll
                for (int nt = 0; nt < 4; ++nt) {
                    int col = wc * 64 + nt * 16 + lrow;
                    int boff = (kx << 12) + (col << 5) + ((lch ^ (col & 3)) << 3);
                    bf16x8 bhf = *(const bf16x8*)(Bb + boff);
                    bf16x8 blf = *(const bf16x8*)(Bb + 12288 + boff);
#pragma unroll
                    for (int yr = 0; yr < 4; ++yr) {
                        acc[yr][nt] = __builtin_amdgcn_mfma_f32_16x16x32_bf16(ahf[yr], bhf, acc[yr][nt], 0, 0, 0);
                        acc[yr][nt] = __builtin_amdgcn_mfma_f32_16x16x32_bf16(ahf[yr], blf, acc[yr][nt], 0, 0, 0);
                        acc[yr][nt] = __builtin_amdgcn_mfma_f32_16x16x32_bf16(alf[yr], bhf, acc[yr][nt], 0, 0, 0);
                    }
                }
            }
            __syncthreads();
        }
    }

    // epilogue: D row = x-pos = 4*lch + j, D col = co = 16*nt + lrow
    int xs4 = x0 + (lch << 2);
#pragma unroll
    for (int nt = 0; nt < 4; ++nt) {
        int co = co0 + wc * 64 + nt * 16 + lrow;
        float dmv = dm[(b << 8) + co];
        float bv = bias[co];
#pragma unroll
        for (int yr = 0; yr < 4; ++yr) {
            int y = y0 + wy * 4 + yr;
            if (y < HO) {
                ushort4 o;
                o.x = f2bf(acc[yr][nt][0] * dmv + bv);
                o.y = f2bf(acc[yr][nt][1] * dmv + bv);
                o.z = f2bf(acc[yr][nt][2] * dmv + bv);
                o.w = f2bf(acc[yr][nt][3] * dmv + bv);
                *(ushort4*)(convout + ((size_t)((b << 8) + co) * HO + y) * CSTRIDE + xs4) = o;
            }
        }
    }
}

// Fused upfirdn(up2,x) -> upfirdn(up2,y) -> leaky*sqrt2 -> down2(x) -> down2(y)
// per (b,c) plane. 62x62 bf16 in (stride-64 rows) -> 64x64 f32 out.
__global__ __launch_bounds__(256) void filter_kernel(
        const unsigned short* __restrict__ convout, const float* __restrict__ upf,
        const float* __restrict__ dnf, float* __restrict__ out) {
    __shared__ float lds0[12214];
    __shared__ __align__(16) float trow2[4][2][144];
    __shared__ float uf[12], df[12];
    float* cin  = lds0;
    float* bufA = lds0 + 4030;
    float* bufB = lds0;
    int tid = threadIdx.x;
    int p = blockIdx.x;
    const unsigned short* src = convout + (size_t)p * (HO * CSTRIDE);
    float* dst = out + (size_t)p * (64 * 64);
    if (tid < 12) { uf[tid] = upf[tid] * 2.f; df[tid] = dnf[tid]; }
    for (int idx = tid; idx < 62 * 16; idx += 256) {
        int y = idx >> 4, q = idx & 15;
        ushort4 v = *(const ushort4*)(src + y * CSTRIDE + q * 4);
        float* c = cin + y * 65 + q * 4;
        c[0] = bf2f(v.x); c[1] = bf2f(v.y); c[2] = bf2f(v.z); c[3] = bf2f(v.w);
    }
    __syncthreads();
    for (int task = tid; task < 62 * 16; task += 256) {
        int y = task >> 4, g = task & 15;
        int base = 4 * g - 4;
        float xv[10];
#pragma unroll
        for (int t = 0; t < 10; ++t) {
            int i = base + t;
            xv[t] = (i >= 0 && i < 62) ? cin[y * 65 + i] : 0.f;
        }
#pragma unroll
        for (int dd = 0; dd < 4; ++dd) {
            float oe = 0.f, oo = 0.f;
#pragma unroll
            for (int v = 0; v < 6; ++v) {
                oe += uf[2 * v + 1] * xv[dd + 5 - v];
                oo += uf[2 * v] * xv[dd + 6 - v];
            }
            int j = 8 * g + 2 * dd;
            bufA[y * 132 + j] = oe;
            bufA[y * 132 + j + 1] = oo;
        }
    }
    __syncthreads();
    int wid = tid >> 6, lane = tid & 63;
    float* tr0 = &trow2[wid][0][0];
    float* tr1 = &trow2[wid][1][0];
    if (lane < 5) { tr0[lane] = 0.f; tr1[lane] = 0.f; }
    if (lane < 7) { tr0[133 + lane] = 0.f; tr1[133 + lane] = 0.f; }
    const float SQ2 = 1.4142135623730951f;
    for (int it = 0; it < 16; ++it) {
        int n = 4 * it + wid;
#pragma unroll
        for (int half = 0; half < 2; ++half) {
            int j = lane + 64 * half;
            float xv[7];
#pragma unroll
            for (int d = 0; d < 7; ++d) {
                int i = n - 4 + d;
                xv[d] = (i >= 0 && i < 62) ? bufA[i * 132 + j] : 0.f;
            }
            float te = 0.f, to = 0.f;
#pragma unroll
            for (int d = 0; d < 6; ++d) te += uf[11 - 2 * d] * xv[d];
#pragma unroll
            for (int d = 1; d < 7; ++d) to += uf[12 - 2 * d] * xv[d];
            te = (te >= 0.f ? te : 0.2f * te) * SQ2;
            to = (to >= 0.f ? to : 0.2f * to) * SQ2;
            tr0[5 + j] = te;
            tr1[5 + j] = to;
        }
        __syncthreads();
        {
            int xo = lane;
            const float2* a0 = (const float2*)&tr0[2 * xo];
            const float2* a1 = (const float2*)&tr1[2 * xo];
            float v0[12], v1[12];
#pragma unroll
            for (int q = 0; q < 6; ++q) {
                float2 u0 = a0[q], u1 = a1[q];
                v0[2 * q] = u0.x; v0[2 * q + 1] = u0.y;
                v1[2 * q] = u1.x; v1[2 * q + 1] = u1.y;
            }
            float s0 = 0.f, s1 = 0.f;
#pragma unroll
            for (int u = 0; u < 12; ++u) {
                s0 += df[u] * v0[11 - u];
                s1 += df[u] * v1[11 - u];
            }
            bufB[(2 * n) * 65 + xo] = s0;
            bufB[(2 * n + 1) * 65 + xo] = s1;
        }
        __syncthreads();
    }
    for (int idx = tid; idx < 64 * 64; idx += 256) {
        int yo = idx >> 6, xx = idx & 63;
        float acc2 = 0.f;
#pragma unroll
        for (int u = 0; u < 12; ++u) {
            int rr = 2 * yo + 6 - u;
            if (rr >= 0 && rr < 128) acc2 += df[u] * bufB[rr * 65 + xx];
        }
        dst[idx] = acc2;
    }
}

extern "C" void kernel_launch(void* const* d_in, const int* in_sizes, int n_in,
                              void* d_out, int out_size, void* d_ws, size_t ws_size,
                              hipStream_t stream) {
    const float* input       = (const float*)d_in[0];
    const float* style       = (const float*)d_in[1];
    const float* conv_weight = (const float*)d_in[2];
    const float* mod_w       = (const float*)d_in[3];
    const float* mod_b       = (const float*)d_in[4];
    const float* bias        = (const float*)d_in[5];
    const float* up_filter   = (const float*)d_in[6];
    const float* down_filter = (const float*)d_in[7];
    float* ws  = (float*)d_ws;
    float* out = (float*)d_out;
    float* s_buf   = ws;
    float* dm      = ws + 2048;
    float* wsq     = ws + 4096;
    unsigned short* whl     = (unsigned short*)(ws + 69632);
    unsigned short* xh      = (unsigned short*)(ws + 659456);
    unsigned short* xl      = (unsigned short*)(ws + 4853760);
    unsigned short* convout = (unsigned short*)(ws + 9048064);

    hipLaunchKernelGGL(mod_kernel, dim3(512), dim3(256), 0, stream, style, mod_w, mod_b, s_buf);
    hipLaunchKernelGGL(wsplit_kernel, dim3(256), dim3(256), 0, stream, conv_weight, wsq, whl);
    hipLaunchKernelGGL(demod_kernel, dim3(512), dim3(256), 0, stream, s_buf, wsq, dm);
    hipLaunchKernelGGL(xsplit_kernel, dim3(512), dim3(256), 0, stream, input, s_buf, xh, xl);
    hipLaunchKernelGGL(conv_mfma, dim3(32, 2, 8), dim3(256), 72192, stream,
                       xh, xl, whl, dm, bias, convout);
    hipLaunchKernelGGL(filter_kernel, dim3(2048), dim3(256), 0, stream,
                       convout, up_filter, down_filter, out);
}

// Round 5
// 182.661 us; speedup vs baseline: 5.0747x; 1.3119x over previous
//
#include <hip/hip_runtime.h>
#include <math.h>

#define B_   8
#define CIN  256
#define COUT 256
#define H_   64
#define W_   64
#define HO   62
#define WO   62
#define SDIM 512

// convout padded: [b][co][62][64] bf16
#define CSTRIDE 64
#define WHL_OFF 589824   // ushorts between wh and wl

typedef __attribute__((ext_vector_type(8))) short bf16x8;
typedef __attribute__((ext_vector_type(4))) float f32x4;

__device__ __forceinline__ unsigned short f2bf(float f) {
    unsigned int u = __float_as_uint(f);
    u += 0x7fffu + ((u >> 16) & 1u);
    return (unsigned short)(u >> 16);
}
__device__ __forceinline__ float bf2f(unsigned short h) {
    return __uint_as_float(((unsigned int)h) << 16);
}

// ws layout (floats):
// s:       [0, 2048)
// dm:      [2048, 4096)
// wsq:     [4096, 69632)
// whl:     [69632, 659456)     (2 * 9*256*256 ushort: wh then wl)
// xh:      [659456, 4853760)   (8*64*64*256 ushort)
// convout: [9048064, 13111296) (8*256*62*64 ushort)

__global__ void mod_kernel(const float* __restrict__ style, const float* __restrict__ mod_w,
                           const float* __restrict__ mod_b, float* __restrict__ s_out) {
    int wid = blockIdx.x * 4 + (threadIdx.x >> 6);
    int lane = threadIdx.x & 63;
    int b = wid >> 8, ci = wid & 255;
    float acc = 0.f;
    const float* st = style + b * SDIM;
    const float* mw = mod_w + ci * SDIM;
    for (int i = 0; i < SDIM; i += 64) acc += st[i + lane] * mw[i + lane];
    for (int m = 32; m >= 1; m >>= 1) acc += __shfl_xor(acc, m, 64);
    if (lane == 0) s_out[wid] = acc * 0.04419417382415922f + mod_b[ci]; // 1/sqrt(512)
}

__global__ void wsplit_kernel(const float* __restrict__ cw, float* __restrict__ wsq,
                              unsigned short* __restrict__ whl) {
    int idx = blockIdx.x * blockDim.x + threadIdx.x; // co*256+ci
    int co = idx >> 8, ci = idx & 255;
    const float* p = cw + (size_t)idx * 9;
    float ss = 0.f;
#pragma unroll
    for (int k = 0; k < 9; ++k) {
        float v = p[k];
        ss += v * v;
        unsigned short h = f2bf(v);
        unsigned short l = f2bf(v - bf2f(h));
        whl[(k * COUT + co) * CIN + ci] = h;
        whl[WHL_OFF + (k * COUT + co) * CIN + ci] = l;
    }
    wsq[idx] = ss;
}

__global__ void demod_kernel(const float* __restrict__ s_in, const float* __restrict__ wsq,
                             float* __restrict__ dm) {
    int wid = blockIdx.x * 4 + (threadIdx.x >> 6);
    int lane = threadIdx.x & 63;
    int b = wid >> 8, co = wid & 255;
    float acc = 0.f;
    for (int i = 0; i < CIN; i += 64) {
        float sv = s_in[b * CIN + i + lane];
        acc += sv * sv * wsq[co * CIN + i + lane];
    }
    for (int m = 32; m >= 1; m >>= 1) acc += __shfl_xor(acc, m, 64);
    if (lane == 0) {
        const float scale = 0.020833333333333332f; // 1/48 = 1/sqrt(2304)
        float demod = rsqrtf(scale * scale * acc + 1e-8f);
        dm[wid] = demod * scale / (1.f + 1e-8f);
    }
}

// Transpose+scale: x[b][ci][y][x] f32 -> xh[b][y][x][ci] bf16 (activations
// quantized once; the dropped x-lo term is covered by the 2-pass error budget).
__global__ __launch_bounds__(256) void xsplit_kernel(
        const float* __restrict__ x, const float* __restrict__ s_in,
        unsigned short* __restrict__ xh) {
    __shared__ float tile[128 * 65];
    __shared__ float s_loc[256];
    int b = blockIdx.x >> 6;
    int y = blockIdx.x & 63;
    int tid = threadIdx.x;
    s_loc[tid] = s_in[(b << 8) + tid];
    __syncthreads();
    for (int half = 0; half < 2; ++half) {
        int cb = half << 7;
        for (int f = tid; f < 2048; f += 256) {
            int ci = f >> 4, x4 = (f & 15) << 2;
            float4 v = *(const float4*)(x + ((((size_t)b << 8) + cb + ci) << 12) + (y << 6) + x4);
            float sv = s_loc[cb + ci];
            float* t = tile + ci * 65 + x4;
            t[0] = v.x * sv; t[1] = v.y * sv; t[2] = v.z * sv; t[3] = v.w * sv;
        }
        __syncthreads();
        for (int g = tid; g < 1024; g += 256) {
            int c = g & 15, xx = g >> 4;   // c: 8-ci chunk, xx: x position
            unsigned int hw[4];
#pragma unroll
            for (int q = 0; q < 4; ++q) {
                float v0 = tile[(c * 8 + 2 * q) * 65 + xx];
                float v1 = tile[(c * 8 + 2 * q + 1) * 65 + xx];
                hw[q] = (unsigned int)f2bf(v0) | ((unsigned int)f2bf(v1) << 16);
            }
            int o = ((((b << 6) + y) << 6) + xx) * 256 + cb + (c << 3);
            *(uint4*)(xh + o) = make_uint4(hw[0], hw[1], hw[2], hw[3]);
        }
        __syncthreads();
    }
}

// Implicit-GEMM modulated conv, 2-pass bf16 MFMA (ah*bh + ah*bl).
// Block: 4 waves (2 wy x 2 wc); tile: 8 y x 16 x x 128 co.
__global__ __launch_bounds__(256) void conv_mfma(
        const unsigned short* __restrict__ xh,
        const unsigned short* __restrict__ whl, const float* __restrict__ dm,
        const float* __restrict__ bias, unsigned short* __restrict__ convout) {
    extern __shared__ short lds[];
    short* Ah = lds;            // [10][18][4 slot][8]
    short* Bb = lds + 5760;     // [2 a][3 kx][128 co][4 slot][8]

    int tid = threadIdx.x;
    int b = blockIdx.z;
    int co0 = blockIdx.y << 7;
    int sx = blockIdx.x & 3, sy = blockIdx.x >> 2;
    int x0 = sx << 4, y0 = sy << 3;
    int wid = tid >> 6, lane = tid & 63;
    int wy = wid >> 1, wc = wid & 1;
    int lrow = lane & 15, lch = lane >> 4;

    // precompute B-staging source offsets (ushort index into whl)
    int bsrc[12];
#pragma unroll
    for (int k = 0; k < 12; ++k) {
        int u = tid + (k << 8);
        int a = (u >= 1536);
        int r = u - a * 1536;
        int kx = r >> 9;
        int col = (r & 511) >> 2;
        int ch = r & 3;
        int cs = ch ^ ((col >> 1) & 3);
        bsrc[k] = a * WHL_OFF + (kx << 16) + ((co0 + col) << 8) + (cs << 3);
    }

    f32x4 acc[4][4];
#pragma unroll
    for (int i = 0; i < 4; ++i)
#pragma unroll
        for (int j = 0; j < 4; ++j) acc[i][j] = (f32x4){0.f, 0.f, 0.f, 0.f};

    for (int ks = 0; ks < 8; ++ks) {
        int ci0 = ks << 5;
#pragma unroll 1
        for (int ky = 0; ky < 3; ++ky) {
            if (ky == 0) {
                // stage A: 10row * 18col * 4 chunks of 8 ci (hi only)
                for (int e = tid; e < 720; e += 256) {
                    int ch = e & 3;
                    int t2 = e >> 2;
                    int col = t2 % 18, row = t2 / 18;
                    int yy = y0 + row, xx = x0 + col;
                    uint4 v = make_uint4(0u, 0u, 0u, 0u);
                    if (yy < 64 && xx < 64)
                        v = *(const uint4*)(xh + ((((b << 6) + yy) << 6) + xx) * 256 + ci0 + (ch << 3));
                    int off = (row * 18 + col) * 32 + ((ch ^ ((col >> 1) & 3)) << 3);
                    *(uint4*)(Ah + off) = v;
                }
            }
            // stage B: 12 uint4 per thread, precomputed sources, linear LDS dest
            int dyn = ky * 196608 + ci0;
#pragma unroll
            for (int k = 0; k < 12; ++k) {
                uint4 v = *(const uint4*)(whl + bsrc[k] + dyn);
                *(uint4*)(Bb + ((tid + (k << 8)) << 3)) = v;
            }
            __syncthreads();
#pragma unroll
            for (int kx = 0; kx < 3; ++kx) {
                int colL = lrow + kx;
                int asw = (lch ^ ((colL >> 1) & 3)) << 3;
                bf16x8 ahf[4];
#pragma unroll
                for (int yr = 0; yr < 4; ++yr) {
                    int rr = wy * 4 + yr + ky;
                    int off = (rr * 18 + colL) * 32 + asw;
                    ahf[yr] = *(const bf16x8*)(Ah + off);
                }
#pragma unroll
                for (int nt = 0; nt < 4; ++nt) {
                    int col = wc * 64 + nt * 16 + lrow;
                    int boff = (kx << 12) + (col << 5) + ((lch ^ ((col >> 1) & 3)) << 3);
                    bf16x8 bhf = *(const bf16x8*)(Bb + boff);
                    bf16x8 blf = *(const bf16x8*)(Bb + 12288 + boff);
#pragma unroll
                    for (int yr = 0; yr < 4; ++yr) {
                        acc[yr][nt] = __builtin_amdgcn_mfma_f32_16x16x32_bf16(ahf[yr], bhf, acc[yr][nt], 0, 0, 0);
                        acc[yr][nt] = __builtin_amdgcn_mfma_f32_16x16x32_bf16(ahf[yr], blf, acc[yr][nt], 0, 0, 0);
                    }
                }
            }
            __syncthreads();
        }
    }

    // epilogue: D row = x-pos = 4*lch + j, D col = co = 16*nt + lrow
    int xs4 = x0 + (lch << 2);
#pragma unroll
    for (int nt = 0; nt < 4; ++nt) {
        int co = co0 + wc * 64 + nt * 16 + lrow;
        float dmv = dm[(b << 8) + co];
        float bv = bias[co];
#pragma unroll
        for (int yr = 0; yr < 4; ++yr) {
            int y = y0 + wy * 4 + yr;
            if (y < HO) {
                ushort4 o;
                o.x = f2bf(acc[yr][nt][0] * dmv + bv);
                o.y = f2bf(acc[yr][nt][1] * dmv + bv);
                o.z = f2bf(acc[yr][nt][2] * dmv + bv);
                o.w = f2bf(acc[yr][nt][3] * dmv + bv);
                *(ushort4*)(convout + ((size_t)((b << 8) + co) * HO + y) * CSTRIDE + xs4) = o;
            }
        }
    }
}

// Fused upfirdn(up2,x) -> upfirdn(up2,y) -> leaky*sqrt2 -> down2(x) -> down2(y)
// per (b,c) plane. 62x62 bf16 in (stride-64 rows) -> 64x64 f32 out.
__global__ __launch_bounds__(256) void filter_kernel(
        const unsigned short* __restrict__ convout, const float* __restrict__ upf,
        const float* __restrict__ dnf, float* __restrict__ out) {
    __shared__ float lds0[12214];
    __shared__ __align__(16) float trow2[4][2][144];
    __shared__ float uf[12], df[12];
    float* cin  = lds0;
    float* bufA = lds0 + 4030;
    float* bufB = lds0;
    int tid = threadIdx.x;
    int p = blockIdx.x;
    const unsigned short* src = convout + (size_t)p * (HO * CSTRIDE);
    float* dst = out + (size_t)p * (64 * 64);
    if (tid < 12) { uf[tid] = upf[tid] * 2.f; df[tid] = dnf[tid]; }
    for (int idx = tid; idx < 62 * 16; idx += 256) {
        int y = idx >> 4, q = idx & 15;
        ushort4 v = *(const ushort4*)(src + y * CSTRIDE + q * 4);
        float* c = cin + y * 65 + q * 4;
        c[0] = bf2f(v.x); c[1] = bf2f(v.y); c[2] = bf2f(v.z); c[3] = bf2f(v.w);
    }
    __syncthreads();
    for (int task = tid; task < 62 * 16; task += 256) {
        int y = task >> 4, g = task & 15;
        int base = 4 * g - 4;
        float xv[10];
#pragma unroll
        for (int t = 0; t < 10; ++t) {
            int i = base + t;
            xv[t] = (i >= 0 && i < 62) ? cin[y * 65 + i] : 0.f;
        }
#pragma unroll
        for (int dd = 0; dd < 4; ++dd) {
            float oe = 0.f, oo = 0.f;
#pragma unroll
            for (int v = 0; v < 6; ++v) {
                oe += uf[2 * v + 1] * xv[dd + 5 - v];
                oo += uf[2 * v] * xv[dd + 6 - v];
            }
            int j = 8 * g + 2 * dd;
            bufA[y * 132 + j] = oe;
            bufA[y * 132 + j + 1] = oo;
        }
    }
    __syncthreads();
    int wid = tid >> 6, lane = tid & 63;
    float* tr0 = &trow2[wid][0][0];
    float* tr1 = &trow2[wid][1][0];
    if (lane < 5) { tr0[lane] = 0.f; tr1[lane] = 0.f; }
    if (lane < 7) { tr0[133 + lane] = 0.f; tr1[133 + lane] = 0.f; }
    const float SQ2 = 1.4142135623730951f;
    for (int it = 0; it < 16; ++it) {
        int n = 4 * it + wid;
#pragma unroll
        for (int half = 0; half < 2; ++half) {
            int j = lane + 64 * half;
            float xv[7];
#pragma unroll
            for (int d = 0; d < 7; ++d) {
                int i = n - 4 + d;
                xv[d] = (i >= 0 && i < 62) ? bufA[i * 132 + j] : 0.f;
            }
            float te = 0.f, to = 0.f;
#pragma unroll
            for (int d = 0; d < 6; ++d) te += uf[11 - 2 * d] * xv[d];
#pragma unroll
            for (int d = 1; d < 7; ++d) to += uf[12 - 2 * d] * xv[d];
            te = (te >= 0.f ? te : 0.2f * te) * SQ2;
            to = (to >= 0.f ? to : 0.2f * to) * SQ2;
            tr0[5 + j] = te;
            tr1[5 + j] = to;
        }
        __syncthreads();
        {
            int xo = lane;
            const float2* a0 = (const float2*)&tr0[2 * xo];
            const float2* a1 = (const float2*)&tr1[2 * xo];
            float v0[12], v1[12];
#pragma unroll
            for (int q = 0; q < 6; ++q) {
                float2 u0 = a0[q], u1 = a1[q];
                v0[2 * q] = u0.x; v0[2 * q + 1] = u0.y;
                v1[2 * q] = u1.x; v1[2 * q + 1] = u1.y;
            }
            float s0 = 0.f, s1 = 0.f;
#pragma unroll
            for (int u = 0; u < 12; ++u) {
                s0 += df[u] * v0[11 - u];
                s1 += df[u] * v1[11 - u];
            }
            bufB[(2 * n) * 65 + xo] = s0;
            bufB[(2 * n + 1) * 65 + xo] = s1;
        }
        __syncthreads();
    }
    for (int idx = tid; idx < 64 * 64; idx += 256) {
        int yo = idx >> 6, xx = idx & 63;
        float acc2 = 0.f;
#pragma unroll
        for (int u = 0; u < 12; ++u) {
            int rr = 2 * yo + 6 - u;
            if (rr >= 0 && rr < 128) acc2 += df[u] * bufB[rr * 65 + xx];
        }
        dst[idx] = acc2;
    }
}

extern "C" void kernel_launch(void* const* d_in, const int* in_sizes, int n_in,
                              void* d_out, int out_size, void* d_ws, size_t ws_size,
                              hipStream_t stream) {
    const float* input       = (const float*)d_in[0];
    const float* style       = (const float*)d_in[1];
    const float* conv_weight = (const float*)d_in[2];
    const float* mod_w       = (const float*)d_in[3];
    const float* mod_b       = (const float*)d_in[4];
    const float* bias        = (const float*)d_in[5];
    const float* up_filter   = (const float*)d_in[6];
    const float* down_filter = (const float*)d_in[7];
    float* ws  = (float*)d_ws;
    float* out = (float*)d_out;
    float* s_buf   = ws;
    float* dm      = ws + 2048;
    float* wsq     = ws + 4096;
    unsigned short* whl     = (unsigned short*)(ws + 69632);
    unsigned short* xh      = (unsigned short*)(ws + 659456);
    unsigned short* convout = (unsigned short*)(ws + 9048064);

    hipLaunchKernelGGL(mod_kernel, dim3(512), dim3(256), 0, stream, style, mod_w, mod_b, s_buf);
    hipLaunchKernelGGL(wsplit_kernel, dim3(256), dim3(256), 0, stream, conv_weight, wsq, whl);
    hipLaunchKernelGGL(demod_kernel, dim3(512), dim3(256), 0, stream, s_buf, wsq, dm);
    hipLaunchKernelGGL(xsplit_kernel, dim3(512), dim3(256), 0, stream, input, s_buf, xh);
    hipLaunchKernelGGL(conv_mfma, dim3(32, 2, 8), dim3(256), 60672, stream,
                       xh, whl, dm, bias, convout);
    hipLaunchKernelGGL(filter_kernel, dim3(2048), dim3(256), 0, stream,
                       convout, up_filter, down_filter, out);
}

// Round 7
// 173.652 us; speedup vs baseline: 5.3380x; 1.0519x over previous
//
#include <hip/hip_runtime.h>
#include <math.h>

#define B_   8
#define CIN  256
#define COUT 256
#define H_   64
#define W_   64
#define HO   62
#define WO   62
#define SDIM 512

// convout padded: [b][co][62][64] bf16
#define CSTRIDE 64
#define WHL_OFF 589824   // ushorts between wh and wl

typedef __attribute__((ext_vector_type(8))) short bf16x8;
typedef __attribute__((ext_vector_type(4))) float f32x4;

__device__ __forceinline__ unsigned short f2bf(float f) {
    unsigned int u = __float_as_uint(f);
    u += 0x7fffu + ((u >> 16) & 1u);
    return (unsigned short)(u >> 16);
}
__device__ __forceinline__ float bf2f(unsigned short h) {
    return __uint_as_float(((unsigned int)h) << 16);
}

// ws layout (floats):
// s:       [0, 2048)
// dm:      [2048, 4096)
// wsq:     [4096, 69632)
// whl:     [69632, 659456)     (2 * 9*256*256 ushort: wh then wl)
// xh:      [659456, 4853760)   (8*64*64*256 ushort)
// convout: [9048064, 13111296) (8*256*62*64 ushort)

__global__ void mod_kernel(const float* __restrict__ style, const float* __restrict__ mod_w,
                           const float* __restrict__ mod_b, float* __restrict__ s_out) {
    int wid = blockIdx.x * 4 + (threadIdx.x >> 6);
    int lane = threadIdx.x & 63;
    int b = wid >> 8, ci = wid & 255;
    float acc = 0.f;
    const float* st = style + b * SDIM;
    const float* mw = mod_w + ci * SDIM;
    for (int i = 0; i < SDIM; i += 64) acc += st[i + lane] * mw[i + lane];
    for (int m = 32; m >= 1; m >>= 1) acc += __shfl_xor(acc, m, 64);
    if (lane == 0) s_out[wid] = acc * 0.04419417382415922f + mod_b[ci]; // 1/sqrt(512)
}

__global__ void wsplit_kernel(const float* __restrict__ cw, float* __restrict__ wsq,
                              unsigned short* __restrict__ whl) {
    int idx = blockIdx.x * blockDim.x + threadIdx.x; // co*256+ci
    int co = idx >> 8, ci = idx & 255;
    const float* p = cw + (size_t)idx * 9;
    float ss = 0.f;
#pragma unroll
    for (int k = 0; k < 9; ++k) {
        float v = p[k];
        ss += v * v;
        unsigned short h = f2bf(v);
        unsigned short l = f2bf(v - bf2f(h));
        whl[(k * COUT + co) * CIN + ci] = h;
        whl[WHL_OFF + (k * COUT + co) * CIN + ci] = l;
    }
    wsq[idx] = ss;
}

__global__ void demod_kernel(const float* __restrict__ s_in, const float* __restrict__ wsq,
                             float* __restrict__ dm) {
    int wid = blockIdx.x * 4 + (threadIdx.x >> 6);
    int lane = threadIdx.x & 63;
    int b = wid >> 8, co = wid & 255;
    float acc = 0.f;
    for (int i = 0; i < CIN; i += 64) {
        float sv = s_in[b * CIN + i + lane];
        acc += sv * sv * wsq[co * CIN + i + lane];
    }
    for (int m = 32; m >= 1; m >>= 1) acc += __shfl_xor(acc, m, 64);
    if (lane == 0) {
        const float scale = 0.020833333333333332f; // 1/48 = 1/sqrt(2304)
        float demod = rsqrtf(scale * scale * acc + 1e-8f);
        dm[wid] = demod * scale / (1.f + 1e-8f);
    }
}

// Transpose+scale: x[b][ci][y][x] f32 -> xh[b][y][x][ci] bf16.
__global__ __launch_bounds__(256) void xsplit_kernel(
        const float* __restrict__ x, const float* __restrict__ s_in,
        unsigned short* __restrict__ xh) {
    __shared__ float tile[128 * 65];
    __shared__ float s_loc[256];
    int b = blockIdx.x >> 6;
    int y = blockIdx.x & 63;
    int tid = threadIdx.x;
    s_loc[tid] = s_in[(b << 8) + tid];
    __syncthreads();
    for (int half = 0; half < 2; ++half) {
        int cb = half << 7;
        for (int f = tid; f < 2048; f += 256) {
            int ci = f >> 4, x4 = (f & 15) << 2;
            float4 v = *(const float4*)(x + ((((size_t)b << 8) + cb + ci) << 12) + (y << 6) + x4);
            float sv = s_loc[cb + ci];
            float* t = tile + ci * 65 + x4;
            t[0] = v.x * sv; t[1] = v.y * sv; t[2] = v.z * sv; t[3] = v.w * sv;
        }
        __syncthreads();
        for (int g = tid; g < 1024; g += 256) {
            int c = g & 15, xx = g >> 4;   // c: 8-ci chunk, xx: x position
            unsigned int hw[4];
#pragma unroll
            for (int q = 0; q < 4; ++q) {
                float v0 = tile[(c * 8 + 2 * q) * 65 + xx];
                float v1 = tile[(c * 8 + 2 * q + 1) * 65 + xx];
                hw[q] = (unsigned int)f2bf(v0) | ((unsigned int)f2bf(v1) << 16);
            }
            int o = ((((b << 6) + y) << 6) + xx) * 256 + cb + (c << 3);
            *(uint4*)(xh + o) = make_uint4(hw[0], hw[1], hw[2], hw[3]);
        }
        __syncthreads();
    }
}

// Implicit-GEMM modulated conv, 2-pass bf16 MFMA (ah*bh + ah*bl).
__global__ __launch_bounds__(256) void conv_mfma(
        const unsigned short* __restrict__ xh,
        const unsigned short* __restrict__ whl, const float* __restrict__ dm,
        const float* __restrict__ bias, unsigned short* __restrict__ convout) {
    extern __shared__ short lds[];
    short* Ah = lds;            // [10][18][4 slot][8]
    short* Bb = lds + 5760;     // [2 a][3 kx][128 co][4 slot][8]

    int tid = threadIdx.x;
    int b = blockIdx.z;
    int co0 = blockIdx.y << 7;
    int sx = blockIdx.x & 3, sy = blockIdx.x >> 2;
    int x0 = sx << 4, y0 = sy << 3;
    int wid = tid >> 6, lane = tid & 63;
    int wy = wid >> 1, wc = wid & 1;
    int lrow = lane & 15, lch = lane >> 4;

    int bsrc[12];
#pragma unroll
    for (int k = 0; k < 12; ++k) {
        int u = tid + (k << 8);
        int a = (u >= 1536);
        int r = u - a * 1536;
        int kx = r >> 9;
        int col = (r & 511) >> 2;
        int ch = r & 3;
        int cs = ch ^ ((col >> 1) & 3);
        bsrc[k] = a * WHL_OFF + (kx << 16) + ((co0 + col) << 8) + (cs << 3);
    }

    f32x4 acc[4][4];
#pragma unroll
    for (int i = 0; i < 4; ++i)
#pragma unroll
        for (int j = 0; j < 4; ++j) acc[i][j] = (f32x4){0.f, 0.f, 0.f, 0.f};

    for (int ks = 0; ks < 8; ++ks) {
        int ci0 = ks << 5;
#pragma unroll 1
        for (int ky = 0; ky < 3; ++ky) {
            if (ky == 0) {
                for (int e = tid; e < 720; e += 256) {
                    int ch = e & 3;
                    int t2 = e >> 2;
                    int col = t2 % 18, row = t2 / 18;
                    int yy = y0 + row, xx = x0 + col;
                    uint4 v = make_uint4(0u, 0u, 0u, 0u);
                    if (yy < 64 && xx < 64)
                        v = *(const uint4*)(xh + ((((b << 6) + yy) << 6) + xx) * 256 + ci0 + (ch << 3));
                    int off = (row * 18 + col) * 32 + ((ch ^ ((col >> 1) & 3)) << 3);
                    *(uint4*)(Ah + off) = v;
                }
            }
            int dyn = ky * 196608 + ci0;
#pragma unroll
            for (int k = 0; k < 12; ++k) {
                uint4 v = *(const uint4*)(whl + bsrc[k] + dyn);
                *(uint4*)(Bb + ((tid + (k << 8)) << 3)) = v;
            }
            __syncthreads();
#pragma unroll
            for (int kx = 0; kx < 3; ++kx) {
                int colL = lrow + kx;
                int asw = (lch ^ ((colL >> 1) & 3)) << 3;
                bf16x8 ahf[4];
#pragma unroll
                for (int yr = 0; yr < 4; ++yr) {
                    int rr = wy * 4 + yr + ky;
                    int off = (rr * 18 + colL) * 32 + asw;
                    ahf[yr] = *(const bf16x8*)(Ah + off);
                }
#pragma unroll
                for (int nt = 0; nt < 4; ++nt) {
                    int col = wc * 64 + nt * 16 + lrow;
                    int boff = (kx << 12) + (col << 5) + ((lch ^ ((col >> 1) & 3)) << 3);
                    bf16x8 bhf = *(const bf16x8*)(Bb + boff);
                    bf16x8 blf = *(const bf16x8*)(Bb + 12288 + boff);
#pragma unroll
                    for (int yr = 0; yr < 4; ++yr) {
                        acc[yr][nt] = __builtin_amdgcn_mfma_f32_16x16x32_bf16(ahf[yr], bhf, acc[yr][nt], 0, 0, 0);
                        acc[yr][nt] = __builtin_amdgcn_mfma_f32_16x16x32_bf16(ahf[yr], blf, acc[yr][nt], 0, 0, 0);
                    }
                }
            }
            __syncthreads();
        }
    }

    int xs4 = x0 + (lch << 2);
#pragma unroll
    for (int nt = 0; nt < 4; ++nt) {
        int co = co0 + wc * 64 + nt * 16 + lrow;
        float dmv = dm[(b << 8) + co];
        float bv = bias[co];
#pragma unroll
        for (int yr = 0; yr < 4; ++yr) {
            int y = y0 + wy * 4 + yr;
            if (y < HO) {
                ushort4 o;
                o.x = f2bf(acc[yr][nt][0] * dmv + bv);
                o.y = f2bf(acc[yr][nt][1] * dmv + bv);
                o.z = f2bf(acc[yr][nt][2] * dmv + bv);
                o.w = f2bf(acc[yr][nt][3] * dmv + bv);
                *(ushort4*)(convout + ((size_t)((b << 8) + co) * HO + y) * CSTRIDE + xs4) = o;
            }
        }
    }
}

// Fused upfirdn chain per (b,c) plane. 62x62 bf16 in -> 64x64 f32 out.
// lds0 (floats): cin [0,4464) 62 rows stride 72 (data cols 4..65, pads zeroed)
//                bufA [4464,13704) 70 rows stride 132 (+4 row offset, pad rows zeroed)
//                bufB aliases lds0[0,8970): 138 rows stride 65 (+5 row offset)
// Aliasing safety (barrier every 4 its, incl. slide read-ahead to row 4it+wid+10):
//  window w writes bufB reach (32w+36)*65+64; lowest bufA float read in window w
//  is 4464+(16w+7)*132: 2404<4464, 4484<7500, 6564<9612, 8644<11724. tr0/tr1 are
//  per-wave (in-wave LDS program order suffices).
// Staging/pad ownership: staging writes cin cols 4..65 ONLY (q==15 writes float2,
//  not float4 — cols 66,67 would race with the pad-zero loop, convout cols 62,63
//  are garbage); pad loop exclusively owns cols 0..3 and 66..69.
__global__ __launch_bounds__(256) void filter_kernel(
        const unsigned short* __restrict__ convout, const float* __restrict__ upf,
        const float* __restrict__ dnf, float* __restrict__ out) {
    __shared__ __align__(16) float lds0[13704];
    __shared__ __align__(16) float trow2[4][2][144];
    __shared__ float uf[12], df[12];
    float* cin  = lds0;
    float* bufA = lds0 + 4464;
    float* bufB = lds0;
    int tid = threadIdx.x;
    int p = blockIdx.x;
    const unsigned short* src = convout + (size_t)p * (HO * CSTRIDE);
    float* dst = out + (size_t)p * (64 * 64);
    if (tid < 12) { uf[tid] = upf[tid] * 2.f; df[tid] = dnf[tid]; }
    // stage cin (stride 72, data at col 4) + zero cin col-pads + bufA row-pads
    for (int idx = tid; idx < 62 * 16; idx += 256) {
        int y = idx >> 4, q = idx & 15;
        ushort4 v = *(const ushort4*)(src + y * CSTRIDE + q * 4);
        if (q < 15) {
            float4 f = make_float4(bf2f(v.x), bf2f(v.y), bf2f(v.z), bf2f(v.w));
            *(float4*)(cin + y * 72 + 4 + q * 4) = f;
        } else {
            // only cols 60,61 are valid data; cols 62,63 are conv garbage
            *(float2*)(cin + y * 72 + 64) = make_float2(bf2f(v.x), bf2f(v.y));
        }
    }
    for (int idx = tid; idx < 62 * 8; idx += 256) {
        int y = idx >> 3, q = idx & 7;
        cin[y * 72 + (q < 4 ? q : 62 + q)] = 0.f;
    }
    for (int idx = tid; idx < 1056; idx += 256) {
        int r = idx / 132, cc = idx - r * 132;
        bufA[(r < 4 ? r : 62 + r) * 132 + cc] = 0.f;
    }
    __syncthreads();
    // up-x: unguarded, writes bufA rows +4
    for (int task = tid; task < 62 * 16; task += 256) {
        int y = task >> 4, g = task & 15;
        const float* crow = cin + y * 72 + 4 * g;   // = col (4g-4)+4
        float xv[10];
#pragma unroll
        for (int t = 0; t < 10; ++t) xv[t] = crow[t];
        float* arow = bufA + (y + 4) * 132 + 8 * g;
#pragma unroll
        for (int dd = 0; dd < 4; ++dd) {
            float oe = 0.f, oo = 0.f;
#pragma unroll
            for (int v = 0; v < 6; ++v) {
                oe += uf[2 * v + 1] * xv[dd + 5 - v];
                oo += uf[2 * v] * xv[dd + 6 - v];
            }
            *(float2*)(arow + 2 * dd) = make_float2(oe, oo);
        }
    }
    __syncthreads();
    // zero bufB bottom pad rows 0..4 (dead cin region; untouched by the loop)
    for (int idx = tid; idx < 325; idx += 256) bufB[idx] = 0.f;

    int wid = tid >> 6, lane = tid & 63;
    float* tr0 = &trow2[wid][0][0];
    float* tr1 = &trow2[wid][1][0];
    if (lane < 5) { tr0[lane] = 0.f; tr1[lane] = 0.f; }
    if (lane < 7) { tr0[133 + lane] = 0.f; tr1[133 + lane] = 0.f; }
    const float SQ2 = 1.4142135623730951f;
    // sliding windows over padded bufA rows [n, n+6], n = 4*it + wid
    float w0[7], w1[7];
#pragma unroll
    for (int d = 0; d < 7; ++d) {
        w0[d] = bufA[(wid + d) * 132 + lane];
        w1[d] = bufA[(wid + d) * 132 + lane + 64];
    }
    for (int it = 0; it < 16; ++it) {
        int n = 4 * it + wid;
        {
            float te0 = 0.f, to0 = 0.f, te1 = 0.f, to1 = 0.f;
#pragma unroll
            for (int d = 0; d < 6; ++d) { te0 += uf[11 - 2 * d] * w0[d]; te1 += uf[11 - 2 * d] * w1[d]; }
#pragma unroll
            for (int d = 1; d < 7; ++d) { to0 += uf[12 - 2 * d] * w0[d]; to1 += uf[12 - 2 * d] * w1[d]; }
            te0 = (te0 >= 0.f ? te0 : 0.2f * te0) * SQ2;
            to0 = (to0 >= 0.f ? to0 : 0.2f * to0) * SQ2;
            te1 = (te1 >= 0.f ? te1 : 0.2f * te1) * SQ2;
            to1 = (to1 >= 0.f ? to1 : 0.2f * to1) * SQ2;
            tr0[5 + lane] = te0;      tr1[5 + lane] = to0;
            tr0[69 + lane] = te1;     tr1[69 + lane] = to1;
        }
        __builtin_amdgcn_wave_barrier();
        {
            int xo = lane;
            const float2* a0 = (const float2*)&tr0[2 * xo];
            const float2* a1 = (const float2*)&tr1[2 * xo];
            float v0[12], v1[12];
#pragma unroll
            for (int q = 0; q < 6; ++q) {
                float2 u0 = a0[q], u1 = a1[q];
                v0[2 * q] = u0.x; v0[2 * q + 1] = u0.y;
                v1[2 * q] = u1.x; v1[2 * q + 1] = u1.y;
            }
            float s0 = 0.f, s1 = 0.f;
#pragma unroll
            for (int u = 0; u < 12; ++u) {
                s0 += df[u] * v0[11 - u];
                s1 += df[u] * v1[11 - u];
            }
            bufB[(2 * n + 5) * 65 + xo] = s0;
            bufB[(2 * n + 6) * 65 + xo] = s1;
        }
        if (it < 15) {
#pragma unroll
            for (int d = 0; d < 3; ++d) { w0[d] = w0[d + 4]; w1[d] = w1[d + 4]; }
#pragma unroll
            for (int d = 3; d < 7; ++d) {
                w0[d] = bufA[(n + 4 + d) * 132 + lane];
                w1[d] = bufA[(n + 4 + d) * 132 + lane + 64];
            }
        }
        if ((it & 3) == 3) __syncthreads();
        else __builtin_amdgcn_wave_barrier();
    }
    // down-y: bottom pad zeroed; only rr>=128 needs a select
    for (int idx = tid; idx < 64 * 64; idx += 256) {
        int yo = idx >> 6, xx = idx & 63;
        float acc2 = 0.f;
#pragma unroll
        for (int u = 0; u < 12; ++u) {
            int rr = 2 * yo + 6 - u;
            float v = (rr < 128) ? bufB[(rr + 5) * 65 + xx] : 0.f;
            acc2 += df[u] * v;
        }
        dst[idx] = acc2;
    }
}

extern "C" void kernel_launch(void* const* d_in, const int* in_sizes, int n_in,
                              void* d_out, int out_size, void* d_ws, size_t ws_size,
                              hipStream_t stream) {
    const float* input       = (const float*)d_in[0];
    const float* style       = (const float*)d_in[1];
    const float* conv_weight = (const float*)d_in[2];
    const float* mod_w       = (const float*)d_in[3];
    const float* mod_b       = (const float*)d_in[4];
    const float* bias        = (const float*)d_in[5];
    const float* up_filter   = (const float*)d_in[6];
    const float* down_filter = (const float*)d_in[7];
    float* ws  = (float*)d_ws;
    float* out = (float*)d_out;
    float* s_buf   = ws;
    float* dm      = ws + 2048;
    float* wsq     = ws + 4096;
    unsigned short* whl     = (unsigned short*)(ws + 69632);
    unsigned short* xh      = (unsigned short*)(ws + 659456);
    unsigned short* convout = (unsigned short*)(ws + 9048064);

    hipLaunchKernelGGL(mod_kernel, dim3(512), dim3(256), 0, stream, style, mod_w, mod_b, s_buf);
    hipLaunchKernelGGL(wsplit_kernel, dim3(256), dim3(256), 0, stream, conv_weight, wsq, whl);
    hipLaunchKernelGGL(demod_kernel, dim3(512), dim3(256), 0, stream, s_buf, wsq, dm);
    hipLaunchKernelGGL(xsplit_kernel, dim3(512), dim3(256), 0, stream, input, s_buf, xh);
    hipLaunchKernelGGL(conv_mfma, dim3(32, 2, 8), dim3(256), 60672, stream,
                       xh, whl, dm, bias, convout);
    hipLaunchKernelGGL(filter_kernel, dim3(2048), dim3(256), 0, stream,
                       convout, up_filter, down_filter, out);
}